// Round 10
// baseline (267.127 us; speedup 1.0000x reference)
//
#include <hip/hip_runtime.h>
#include <hip/hip_bf16.h>

#define EPSF 1e-5f

typedef __attribute__((ext_vector_type(8))) short bf16x8;
typedef __attribute__((ext_vector_type(4))) float f32x4;
typedef __attribute__((ext_vector_type(2))) unsigned int u32x2;
typedef __attribute__((ext_vector_type(4))) unsigned int u32x4;
typedef __attribute__((ext_vector_type(4))) int i32x4;

constexpr int B_ = 2, N_ = 16384;
constexpr int HSTR = 72;   // hbuf row stride (bf16 elems)
constexpr int RSTR = 72;
constexpr int PPW  = 16;   // points per wave
constexpr int NW   = 4;    // waves per block (256 threads)
constexpr int PPB  = 64;   // points per block
constexpr int NWG  = (B_ * N_) / PPB;   // 512 blocks
constexpr int HALF = NWG / 2;           // blocks per batch
constexpr size_t PP_BYTES = (size_t)B_ * N_ * 16;   // 512 KiB padded points

__device__ __forceinline__ short f2bf(float f) {
    __hip_bfloat16 h = __float2bfloat16(f);
    short s; __builtin_memcpy(&s, &h, 2); return s;
}
// packed f32x2 -> bf16x2 (v_cvt_pk_bf16_f32)
__device__ __forceinline__ unsigned int pkbf(float a, float b) {
    float2 f2; f2.x = a; f2.y = b;
    __hip_bfloat162 h = __float22bfloat162_rn(f2);
    unsigned int u; __builtin_memcpy(&u, &h, 4); return u;
}

// prep: points -> padded float4 (one dwordx4 gather instead of 3 divergent dwords)
__global__ __launch_bounds__(256) void prep_points(
    const float* __restrict__ pts, float* __restrict__ pp)
{
    const int i = blockIdx.x * 256 + threadIdx.x;
    if (i < B_ * N_) {
        f32x4 o = { pts[3 * i], pts[3 * i + 1], pts[3 * i + 2], 0.f };
        ((f32x4*)pp)[i] = o;
    }
}

// bridgenet16 vs bridgenet15 (R9 post-mortem: spill came from the SCHEDULE's
// register peak -- LOADD(B) issued before the A-FRONTRs kept 4 f4 sets
// (128 VGPR) live on top of sp/mk[4][4]; allocator stopped at 128 arch
// VGPRs and spilled 300 MB of scratch. FRONTR/BACKQ themselves SAVE regs
// (sp/mk = 8/point vs acc2's 32)):
//  - R8 LOAD PLACEMENT: each LOADD issued right after the FRONTR that
//    frees its destination registers, one FRONTR (~700cy) ahead of its
//    consumer. Worst-case live ~3 f4 sets (96) + sp/mk(32) + resid(24)
//    + weights (~60) ~ 210: no 4-set peak by construction.
//  - kept from R9: FRONTR (local h2/sp/mk reduce folded into FRONT),
//    BACKQ (4-point batched cross-lane softmax: 32 independent shfl
//    chains, 4 independent exp->tree->rcp chains).
//  - kept from R8: geometry (512 blk x 4 waves x PPW=16), saddr gathers,
//    sqrtf/rcpf, XCD swizzle, setprio, wb2/wb3 staging, launch_bounds(256,2).
template<bool PAD>
__global__ __launch_bounds__(256, 2) void bridgenet16(
    const float* __restrict__ points,     // raw (PAD=false)
    const float* __restrict__ pp,         // padded float4 (PAD=true)
    const float* __restrict__ features,
    const int*   __restrict__ gidx,
    const float* __restrict__ Wpos,
    const float* __restrict__ bposv,
    const float* __restrict__ bn1g, const float* __restrict__ bn1b,
    const float* __restrict__ bn1m, const float* __restrict__ bn1v,
    const float* __restrict__ Wgcm,
    const float* __restrict__ bgcm,
    const float* __restrict__ bn2g, const float* __restrict__ bn2b,
    const float* __restrict__ bn2m, const float* __restrict__ bn2v,
    const float* __restrict__ Watt,
    const float* __restrict__ batt,
    const float* __restrict__ Wout,
    const float* __restrict__ bout,
    const float* __restrict__ lng, const float* __restrict__ lnb,
    float* __restrict__ out)
{
    __shared__ __align__(16) short hbuf[NW][2][32 * HSTR];    // 36864 B
    __shared__ __align__(16) short resstage[PPB * RSTR];      //  9216 B
    __shared__ __align__(16) short wb2[8 * 64 * 8];           //  8192 B
    __shared__ __align__(16) short wb3[8 * 64 * 8];           //  8192 B

    const int t    = threadIdx.x;
    const int w    = t >> 6;
    const int l    = t & 63;
    const int l15  = l & 15;
    const int quad = l >> 4;
    const int c4   = l15 * 4;

    // ---- XCD batch-affinity swizzle (round-robin wg%8 -> XCD) ----
    const int wg  = blockIdx.x;
    const int blk = ((wg & 7) >> 2) * HALF + ((wg >> 3) << 2) + (wg & 3);

    // ---- cooperative weight staging: 16 frag-sets, 4 per wave ----
    {
        #pragma unroll
        for (int u = 0; u < 4; ++u) {
            const int s  = w * 4 + u;          // 0..15
            const int nt = (s >> 1) & 3, ks = s & 1;
            const float* src = (s < 8 ? Wgcm : Wout) + (c4 + nt) * 64 + ks * 32 + quad * 8;
            const f32x4 w0 = *(const f32x4*)src;
            const f32x4 w1 = *(const f32x4*)(src + 4);
            bf16x8 f;
            #pragma unroll
            for (int j = 0; j < 4; ++j) {
                f[j]     = f2bf(w0[j]);
                f[j + 4] = f2bf(w1[j]);
            }
            short* dst = (s < 8 ? wb2 : wb3);
            *(bf16x8*)&dst[((s & 7) * 64 + l) * 8] = f;
        }
    }

    // ---- per-wave constant state ----
    bf16x8 bposf[4];
    #pragma unroll
    for (int nt = 0; nt < 4; ++nt) {
        const int c = c4 + nt;
        #pragma unroll
        for (int j = 0; j < 8; ++j) {
            const int g = quad * 8 + j;
            bposf[nt][j] = f2bf(g < 10 ? Wpos[c * 10 + g] : 0.f);
        }
    }
    f32x4 ps1, pb1, ps2, pb2;
    {
        const f32x4 g1 = *(const f32x4*)(bn1g + c4);
        const f32x4 b1 = *(const f32x4*)(bn1b + c4);
        const f32x4 m1 = *(const f32x4*)(bn1m + c4);
        const f32x4 v1 = *(const f32x4*)(bn1v + c4);
        const f32x4 bp = *(const f32x4*)(bposv + c4);
        const f32x4 g2 = *(const f32x4*)(bn2g + c4);
        const f32x4 b2 = *(const f32x4*)(bn2b + c4);
        const f32x4 m2 = *(const f32x4*)(bn2m + c4);
        const f32x4 v2 = *(const f32x4*)(bn2v + c4);
        const f32x4 bg = *(const f32x4*)(bgcm + c4);
        #pragma unroll
        for (int j = 0; j < 4; ++j) {
            ps1[j] = g1[j] * rsqrtf(v1[j] + EPSF);
            pb1[j] = ps1[j] * (bp[j] - m1[j]) + b1[j];
            ps2[j] = g2[j] * rsqrtf(v2[j] + EPSF);
            pb2[j] = ps2[j] * (bg[j] - m2[j]) + b2[j];
        }
    }
    float wat[2][4];
    #pragma unroll
    for (int mt = 0; mt < 2; ++mt)
        #pragma unroll
        for (int r = 0; r < 4; ++r)
            wat[mt][r] = Watt[mt * 16 + quad * 4 + r];
    const float battv = batt[0];

    const f32x4 zero4 = {0.f, 0.f, 0.f, 0.f};
    const int base = blk * PPB + w * PPW;
    const int bb   = ((blk * PPB) >> 14) * N_;   // batch base (blocks don't straddle)

    // ---- wave-uniform SGPR bases: gathers become saddr + 32-bit voffset ----
    const float* __restrict__ fb  = features + (size_t)bb * 64;  // batch features
    const float* __restrict__ ppb = pp + (size_t)bb * 4;         // batch padded pts
    const int*   __restrict__ gb  = gidx + (size_t)base * 32;    // this wave's idx rows

    // ---- pipeline helpers ----
    auto LOADI = [&](int i, i32x4 (&gi)[2]) {
        gi[0] = *(const i32x4*)(gb + i * 32 + quad * 4);
        gi[1] = *(const i32x4*)(gb + i * 32 + 16 + quad * 4);
    };
    auto LOADD = [&](int i, const i32x4 (&gi)[2],
                     f32x4 (&f4)[2][4], bf16x8 (&ageo)[2], f32x4& resid) {
        #pragma unroll
        for (int mt = 0; mt < 2; ++mt)
            #pragma unroll
            for (int r = 0; r < 4; ++r)
                f4[mt][r] = *(const f32x4*)(fb + (((unsigned)gi[mt][r]) << 6) + c4);
        const int pt = base + i;
        resid = *(const f32x4*)(features + (size_t)pt * 64 + c4);
        int gv[2];
        gv[0] = gb[i * 32 + l15];
        gv[1] = gb[i * 32 + 16 + l15];
        float xi0, xi1, xi2, px[2], py[2], pz[2];
        if (PAD) {
            const f32x4 x4 = *(const f32x4*)(pp + (size_t)pt * 4);
            xi0 = x4[0]; xi1 = x4[1]; xi2 = x4[2];
            #pragma unroll
            for (int mt = 0; mt < 2; ++mt) {
                const f32x4 p4 = *(const f32x4*)(ppb + (((unsigned)gv[mt]) << 2));
                px[mt] = p4[0]; py[mt] = p4[1]; pz[mt] = p4[2];
            }
        } else {
            xi0 = points[(size_t)pt * 3];
            xi1 = points[(size_t)pt * 3 + 1];
            xi2 = points[(size_t)pt * 3 + 2];
            #pragma unroll
            for (int mt = 0; mt < 2; ++mt) {
                const float* ppt = points + (size_t)(bb + gv[mt]) * 3;
                px[mt] = ppt[0]; py[mt] = ppt[1]; pz[mt] = ppt[2];
            }
        }
        #pragma unroll
        for (int mt = 0; mt < 2; ++mt) {
            const float dx = xi0 - px[mt], dy = xi1 - py[mt], dz = xi2 - pz[mt];
            const float dist = __builtin_amdgcn_sqrtf(dx * dx + dy * dy + dz * dz);
            u32x4 u = {0u, 0u, 0u, 0u};
            if (quad == 0) {
                u[0] = pkbf(xi0, xi1); u[1] = pkbf(xi2, px[mt]);
                u[2] = pkbf(py[mt], pz[mt]); u[3] = pkbf(dx, dy);
            } else if (quad == 1) {
                u[0] = pkbf(dz, dist);
            }
            __builtin_memcpy(&ageo[mt], &u, 16);
        }
    };

    // FRONTR: pos-MLP MFMA + epi1 (hbuf) + GCM MFMAs + LOCAL h2/sp/mk reduce.
    auto FRONTR = [&](short* hb, const f32x4 (&f4)[2][4], const bf16x8 (&ageo)[2],
                      float (&sp)[4], float (&mk)[4]) {
        __builtin_amdgcn_s_setprio(1);
        f32x4 acc1[2][4];
        #pragma unroll
        for (int mt = 0; mt < 2; ++mt)
            #pragma unroll
            for (int nt = 0; nt < 4; ++nt)
                acc1[mt][nt] = __builtin_amdgcn_mfma_f32_16x16x32_bf16(
                    ageo[mt], bposf[nt], zero4, 0, 0, 0);
        __builtin_amdgcn_s_setprio(0);

        #pragma unroll
        for (int mt = 0; mt < 2; ++mt)
            #pragma unroll
            for (int r = 0; r < 4; ++r) {
                const int k = mt * 16 + quad * 4 + r;
                float v[4];
                #pragma unroll
                for (int j = 0; j < 4; ++j)
                    v[j] = f4[mt][r][j] + fmaxf(ps1[j] * acc1[mt][j][r] + pb1[j], 0.f);
                u32x2 hv = { pkbf(v[0], v[1]), pkbf(v[2], v[3]) };
                *(u32x2*)&hb[k * HSTR + c4] = hv;
            }

        bf16x8 a2[2][2];
        #pragma unroll
        for (int mt = 0; mt < 2; ++mt)
            #pragma unroll
            for (int ks = 0; ks < 2; ++ks)
                a2[mt][ks] = *(const bf16x8*)&hb[(mt * 16 + l15) * HSTR + ks * 32 + quad * 8];
        __builtin_amdgcn_s_setprio(1);
        f32x4 acc2[2][4];
        #pragma unroll
        for (int nt = 0; nt < 4; ++nt) {
            const bf16x8 b0 = *(const bf16x8*)&wb2[((nt * 2 + 0) * 64 + l) * 8];
            const bf16x8 b1 = *(const bf16x8*)&wb2[((nt * 2 + 1) * 64 + l) * 8];
            #pragma unroll
            for (int mt = 0; mt < 2; ++mt) {
                f32x4 a = __builtin_amdgcn_mfma_f32_16x16x32_bf16(a2[mt][0], b0, zero4, 0, 0, 0);
                acc2[mt][nt] = __builtin_amdgcn_mfma_f32_16x16x32_bf16(a2[mt][1], b1, a, 0, 0, 0);
            }
        }
        __builtin_amdgcn_s_setprio(0);

        #pragma unroll
        for (int nt = 0; nt < 4; ++nt) {
            sp[nt] = 0.f; mk[nt] = 0.f;
            #pragma unroll
            for (int mt = 0; mt < 2; ++mt)
                #pragma unroll
                for (int r = 0; r < 4; ++r) {
                    const float h2 = fmaxf(ps2[nt] * acc2[mt][nt][r] + pb2[nt], 0.f);
                    sp[nt] += h2 * wat[mt][r];
                    mk[nt] = fmaxf(mk[nt], h2);
                }
        }
    };

    // BACKQ: cross-lane softmax for FOUR points batched -> 4-way ILP on the
    // shfl/exp/rcp chains.
    auto BACKQ = [&](int i0, float (&sp)[4][4], float (&mk)[4][4],
                     const f32x4& r0, const f32x4& r1,
                     const f32x4& r2, const f32x4& r3) {
        #pragma unroll
        for (int j = 0; j < 4; ++j)
            #pragma unroll
            for (int nt = 0; nt < 4; ++nt) {
                sp[j][nt] += __shfl_xor(sp[j][nt], 16);
                sp[j][nt] += __shfl_xor(sp[j][nt], 32);
                mk[j][nt] = fmaxf(mk[j][nt], __shfl_xor(mk[j][nt], 16));
                mk[j][nt] = fmaxf(mk[j][nt], __shfl_xor(mk[j][nt], 32));
            }
        float e[4][4], s[4];
        #pragma unroll
        for (int j = 0; j < 4; ++j) {
            s[j] = 0.f;
            #pragma unroll
            for (int nt = 0; nt < 4; ++nt) {
                e[j][nt] = __expf(sp[j][nt] + battv);
                s[j] += e[j][nt];
            }
        }
        #pragma unroll
        for (int o = 1; o < 16; o <<= 1)
            #pragma unroll
            for (int j = 0; j < 4; ++j)
                s[j] += __shfl_xor(s[j], o);
        const f32x4* rs[4] = { &r0, &r1, &r2, &r3 };
        #pragma unroll
        for (int j = 0; j < 4; ++j) {
            const float inv = __builtin_amdgcn_rcpf(s[j]);
            float res[4];
            #pragma unroll
            for (int nt = 0; nt < 4; ++nt)
                res[nt] = e[j][nt] * inv * mk[j][nt] + (*rs[j])[nt];
            if (quad == 0) {
                u32x2 rv = { pkbf(res[0], res[1]), pkbf(res[2], res[3]) };
                *(u32x2*)&resstage[(w * PPW + i0 + j) * RSTR + c4] = rv;
            }
        }
    };

    short* hb0 = &hbuf[w][0][0];
    short* hb1 = &hbuf[w][1][0];

    // ---- prologue: indices for points 0..3, data for pair A (0,1) ----
    i32x4 giA0[2], giA1[2], giB0[2], giB1[2];
    LOADI(0, giA0); LOADI(1, giA1); LOADI(2, giB0); LOADI(3, giB1);
    f32x4  f4A0[2][4], f4A1[2][4], f4B0[2][4], f4B1[2][4];
    bf16x8 agA0[2], agA1[2], agB0[2], agB1[2];
    f32x4  rA0, rA1, rB0, rB1, rN0, rN1;
    LOADD(0, giA0, f4A0, agA0, rA0);
    LOADD(1, giA1, f4A1, agA1, rA1);

    __syncthreads();   // weight LDS ready

    // ---- main loop: 4 points / iter, LOADDs staggered one FRONTR ahead ----
    for (int ip = 0; ip < PPW; ip += 4) {
        float sp[4][4], mk[4][4];

        FRONTR(hb0, f4A0, agA0, sp[0], mk[0]);       // frees f4A0
        LOADD(ip + 2, giB0, f4B0, agB0, rB0);        // covered by FRONTR(A1)
        FRONTR(hb1, f4A1, agA1, sp[1], mk[1]);       // frees f4A1
        LOADD(ip + 3, giB1, f4B1, agB1, rB1);        // covered by FRONTR(B0)
        if (ip + 4 < PPW) { LOADI(ip + 4, giA0); LOADI(ip + 5, giA1); }

        FRONTR(hb0, f4B0, agB0, sp[2], mk[2]);       // frees f4B0
        if (ip + 4 < PPW)
            LOADD(ip + 4, giA0, f4A0, agA0, rN0);    // covered by FRONTR(B1)+BACKQ
        FRONTR(hb1, f4B1, agB1, sp[3], mk[3]);       // frees f4B1
        if (ip + 4 < PPW) {
            LOADD(ip + 5, giA1, f4A1, agA1, rN1);    // covered by BACKQ
            LOADI(ip + 6, giB0); LOADI(ip + 7, giB1);
        }

        BACKQ(ip, sp, mk, rA0, rA1, rB0, rB1);

        rA0 = rN0; rA1 = rN1;   // only carried rotate (8 v_mov / 4 points)
    }

    __syncthreads();

    // ---------- phase D: batched out-matmul + LayerNorm + relu ----------
    // 4 groups of 16 points; wave w -> group w, all 4 LN rows
    {
        const f32x4 lngv  = *(const f32x4*)(lng + c4);
        const f32x4 lnbv  = *(const f32x4*)(lnb + c4);
        const f32x4 boutv = *(const f32x4*)(bout + c4);
        bf16x8 a3[2];
        #pragma unroll
        for (int ks = 0; ks < 2; ++ks)
            a3[ks] = *(const bf16x8*)&resstage[(w * 16 + l15) * RSTR + ks * 32 + quad * 8];
        f32x4 acc3[4];
        #pragma unroll
        for (int nt = 0; nt < 4; ++nt) {
            const bf16x8 b0 = *(const bf16x8*)&wb3[((nt * 2 + 0) * 64 + l) * 8];
            const bf16x8 b1 = *(const bf16x8*)&wb3[((nt * 2 + 1) * 64 + l) * 8];
            f32x4 a = __builtin_amdgcn_mfma_f32_16x16x32_bf16(a3[0], b0, zero4, 0, 0, 0);
            acc3[nt] = __builtin_amdgcn_mfma_f32_16x16x32_bf16(a3[1], b1, a, 0, 0, 0);
        }
        #pragma unroll
        for (int u = 0; u < 4; ++u) {
            float y[4], s = 0.f;
            #pragma unroll
            for (int nt = 0; nt < 4; ++nt) { y[nt] = acc3[nt][u] + boutv[nt]; s += y[nt]; }
            #pragma unroll
            for (int o = 1; o < 16; o <<= 1) s += __shfl_xor(s, o);
            const float mu = s * (1.f / 64.f);
            float dv[4], v2 = 0.f;
            #pragma unroll
            for (int nt = 0; nt < 4; ++nt) { dv[nt] = y[nt] - mu; v2 += dv[nt] * dv[nt]; }
            #pragma unroll
            for (int o = 1; o < 16; o <<= 1) v2 += __shfl_xor(v2, o);
            const float rs = rsqrtf(v2 * (1.f / 64.f) + EPSF);
            const int pto = blk * PPB + w * 16 + quad * 4 + u;
            f32x4 ov;
            #pragma unroll
            for (int nt = 0; nt < 4; ++nt)
                ov[nt] = fmaxf(lngv[nt] * dv[nt] * rs + lnbv[nt], 0.f);
            *(f32x4*)(out + (size_t)pto * 64 + c4) = ov;
        }
    }
}

extern "C" void kernel_launch(void* const* d_in, const int* in_sizes, int n_in,
                              void* d_out, int out_size, void* d_ws, size_t ws_size,
                              hipStream_t stream) {
    const float* points   = (const float*)d_in[0];
    const float* features = (const float*)d_in[1];
    const int*   gidxp    = (const int*)d_in[2];
    const bool   pad      = (ws_size >= PP_BYTES);
    float* pp = (float*)d_ws;
    if (pad) {
        hipLaunchKernelGGL(prep_points, dim3((B_ * N_ + 255) / 256), dim3(256), 0, stream,
                           points, pp);
        hipLaunchKernelGGL((bridgenet16<true>), dim3(NWG), dim3(256), 0, stream,
            points, pp, features, gidxp,
            (const float*)d_in[3],  (const float*)d_in[4],
            (const float*)d_in[5],  (const float*)d_in[6],  (const float*)d_in[7],  (const float*)d_in[8],
            (const float*)d_in[9],  (const float*)d_in[10],
            (const float*)d_in[11], (const float*)d_in[12], (const float*)d_in[13], (const float*)d_in[14],
            (const float*)d_in[15], (const float*)d_in[16],
            (const float*)d_in[17], (const float*)d_in[18],
            (const float*)d_in[19], (const float*)d_in[20],
            (float*)d_out);
    } else {
        hipLaunchKernelGGL((bridgenet16<false>), dim3(NWG), dim3(256), 0, stream,
            points, pp, features, gidxp,
            (const float*)d_in[3],  (const float*)d_in[4],
            (const float*)d_in[5],  (const float*)d_in[6],  (const float*)d_in[7],  (const float*)d_in[8],
            (const float*)d_in[9],  (const float*)d_in[10],
            (const float*)d_in[11], (const float*)d_in[12], (const float*)d_in[13], (const float*)d_in[14],
            (const float*)d_in[15], (const float*)d_in[16],
            (const float*)d_in[17], (const float*)d_in[18],
            (const float*)d_in[19], (const float*)d_in[20],
            (float*)d_out);
    }
}

// Round 11
// 152.023 us; speedup vs baseline: 1.7572x; 1.7572x over previous
//
#include <hip/hip_runtime.h>
#include <hip/hip_bf16.h>

#define EPSF 1e-5f

typedef __attribute__((ext_vector_type(8))) short bf16x8;
typedef __attribute__((ext_vector_type(4))) float f32x4;
typedef __attribute__((ext_vector_type(2))) unsigned int u32x2;
typedef __attribute__((ext_vector_type(4))) unsigned int u32x4;
typedef __attribute__((ext_vector_type(4))) int i32x4;

constexpr int B_ = 2, N_ = 16384;
constexpr int HSTR = 72;   // hbuf row stride (bf16 elems)
constexpr int RSTR = 72;
constexpr int PPW  = 16;   // points per wave   (paired: 8 pairs)
constexpr int NW   = 4;    // waves per block   (256 threads)
constexpr int PPB  = 64;   // points per block
constexpr int NWG  = (B_ * N_) / PPB;   // 512 blocks
constexpr int HALF = NWG / 2;           // blocks per batch
constexpr size_t PP_BYTES = (size_t)B_ * N_ * 16;   // 512 KiB padded points

__device__ __forceinline__ short f2bf(float f) {
    __hip_bfloat16 h = __float2bfloat16(f);
    short s; __builtin_memcpy(&s, &h, 2); return s;
}
// packed f32x2 -> bf16x2 (v_cvt_pk_bf16_f32)
__device__ __forceinline__ unsigned int pkbf(float a, float b) {
    float2 f2; f2.x = a; f2.y = b;
    __hip_bfloat162 h = __float22bfloat162_rn(f2);
    unsigned int u; __builtin_memcpy(&u, &h, 4); return u;
}

// prep: points -> padded float4 (one dwordx4 gather instead of 3 divergent dwords)
__global__ __launch_bounds__(256) void prep_points(
    const float* __restrict__ pts, float* __restrict__ pp)
{
    const int i = blockIdx.x * 256 + threadIdx.x;
    if (i < B_ * N_) {
        f32x4 o = { pts[3 * i], pts[3 * i + 1], pts[3 * i + 2], 0.f };
        ((f32x4*)pp)[i] = o;
    }
}

// bridgenet14 (VERBATIM REVERT, R10 post-mortem): the R9/R10 4-point
// FRONTR/BACKQ structure spills (WRITE 303/337 MB) regardless of source
// ordering -- the compiler hoists all four LOADD gather clusters above the
// consuming FRONTRs, recreating the 4xf4 register peak; allocator caps at
// 128 arch VGPRs for this shape. Two-point pairing (this kernel) is the
// practical optimum of the chain-ILP lever: 56.2 us dispatch / 152.6 bench.
//  - TWO-POINT PAIRING: body split into FRONT (MFMA1+epi1+GCM, LDS) and
//    BACK (softmax, reg/shfl-only). Order FRONT(A0);FRONT(A1);LOADD(next);
//    BACK(A0);BACK(A1) gives the scheduler two independent streams.
//  - 2 hbuf slots/wave; NW=4, PPW=16, PPB=64, 512 blocks, 256 threads.
//  - saddr addressing (wave-uniform SGPR bases + 32-bit voffsets),
//    sqrtf/rcpf intrinsics, XCD batch-affinity swizzle, setprio on MFMA,
//    coop wb2/wb3 staging, launch_bounds(256,2).
template<bool PAD>
__global__ __launch_bounds__(256, 2) void bridgenet14(
    const float* __restrict__ points,     // raw (PAD=false)
    const float* __restrict__ pp,         // padded float4 (PAD=true)
    const float* __restrict__ features,
    const int*   __restrict__ gidx,
    const float* __restrict__ Wpos,
    const float* __restrict__ bposv,
    const float* __restrict__ bn1g, const float* __restrict__ bn1b,
    const float* __restrict__ bn1m, const float* __restrict__ bn1v,
    const float* __restrict__ Wgcm,
    const float* __restrict__ bgcm,
    const float* __restrict__ bn2g, const float* __restrict__ bn2b,
    const float* __restrict__ bn2m, const float* __restrict__ bn2v,
    const float* __restrict__ Watt,
    const float* __restrict__ batt,
    const float* __restrict__ Wout,
    const float* __restrict__ bout,
    const float* __restrict__ lng, const float* __restrict__ lnb,
    float* __restrict__ out)
{
    __shared__ __align__(16) short hbuf[NW][2][32 * HSTR];    // 36864 B (2 slots/wave)
    __shared__ __align__(16) short resstage[PPB * RSTR];      //  9216 B
    __shared__ __align__(16) short wb2[8 * 64 * 8];           //  8192 B
    __shared__ __align__(16) short wb3[8 * 64 * 8];           //  8192 B

    const int t    = threadIdx.x;
    const int w    = t >> 6;
    const int l    = t & 63;
    const int l15  = l & 15;
    const int quad = l >> 4;
    const int c4   = l15 * 4;

    // ---- XCD batch-affinity swizzle (round-robin wg%8 -> XCD) ----
    const int wg  = blockIdx.x;
    const int blk = ((wg & 7) >> 2) * HALF + ((wg >> 3) << 2) + (wg & 3);

    // ---- cooperative weight staging: 16 frag-sets, 4 per wave ----
    {
        #pragma unroll
        for (int u = 0; u < 4; ++u) {
            const int s  = w * 4 + u;          // 0..15
            const int nt = (s >> 1) & 3, ks = s & 1;
            const float* src = (s < 8 ? Wgcm : Wout) + (c4 + nt) * 64 + ks * 32 + quad * 8;
            const f32x4 w0 = *(const f32x4*)src;
            const f32x4 w1 = *(const f32x4*)(src + 4);
            bf16x8 f;
            #pragma unroll
            for (int j = 0; j < 4; ++j) {
                f[j]     = f2bf(w0[j]);
                f[j + 4] = f2bf(w1[j]);
            }
            short* dst = (s < 8 ? wb2 : wb3);
            *(bf16x8*)&dst[((s & 7) * 64 + l) * 8] = f;
        }
    }

    // ---- per-wave constant state ----
    bf16x8 bposf[4];
    #pragma unroll
    for (int nt = 0; nt < 4; ++nt) {
        const int c = c4 + nt;
        #pragma unroll
        for (int j = 0; j < 8; ++j) {
            const int g = quad * 8 + j;
            bposf[nt][j] = f2bf(g < 10 ? Wpos[c * 10 + g] : 0.f);
        }
    }
    f32x4 ps1, pb1, ps2, pb2;
    {
        const f32x4 g1 = *(const f32x4*)(bn1g + c4);
        const f32x4 b1 = *(const f32x4*)(bn1b + c4);
        const f32x4 m1 = *(const f32x4*)(bn1m + c4);
        const f32x4 v1 = *(const f32x4*)(bn1v + c4);
        const f32x4 bp = *(const f32x4*)(bposv + c4);
        const f32x4 g2 = *(const f32x4*)(bn2g + c4);
        const f32x4 b2 = *(const f32x4*)(bn2b + c4);
        const f32x4 m2 = *(const f32x4*)(bn2m + c4);
        const f32x4 v2 = *(const f32x4*)(bn2v + c4);
        const f32x4 bg = *(const f32x4*)(bgcm + c4);
        #pragma unroll
        for (int j = 0; j < 4; ++j) {
            ps1[j] = g1[j] * rsqrtf(v1[j] + EPSF);
            pb1[j] = ps1[j] * (bp[j] - m1[j]) + b1[j];
            ps2[j] = g2[j] * rsqrtf(v2[j] + EPSF);
            pb2[j] = ps2[j] * (bg[j] - m2[j]) + b2[j];
        }
    }
    float wat[2][4];
    #pragma unroll
    for (int mt = 0; mt < 2; ++mt)
        #pragma unroll
        for (int r = 0; r < 4; ++r)
            wat[mt][r] = Watt[mt * 16 + quad * 4 + r];
    const float battv = batt[0];

    const f32x4 zero4 = {0.f, 0.f, 0.f, 0.f};
    const int base = blk * PPB + w * PPW;
    const int bb   = ((blk * PPB) >> 14) * N_;   // batch base (blocks don't straddle)

    // ---- wave-uniform SGPR bases: gathers become saddr + 32-bit voffset ----
    const float* __restrict__ fb  = features + (size_t)bb * 64;  // batch features
    const float* __restrict__ ppb = pp + (size_t)bb * 4;         // batch padded pts
    const int*   __restrict__ gb  = gidx + (size_t)base * 32;    // this wave's idx rows

    // ---- pipeline helpers ----
    auto LOADI = [&](int i, i32x4 (&gi)[2]) {
        gi[0] = *(const i32x4*)(gb + i * 32 + quad * 4);
        gi[1] = *(const i32x4*)(gb + i * 32 + 16 + quad * 4);
    };
    auto LOADD = [&](int i, const i32x4 (&gi)[2],
                     f32x4 (&f4)[2][4], bf16x8 (&ageo)[2], f32x4& resid) {
        #pragma unroll
        for (int mt = 0; mt < 2; ++mt)
            #pragma unroll
            for (int r = 0; r < 4; ++r)
                f4[mt][r] = *(const f32x4*)(fb + (((unsigned)gi[mt][r]) << 6) + c4);
        const int pt = base + i;
        resid = *(const f32x4*)(features + (size_t)pt * 64 + c4);
        int gv[2];
        gv[0] = gb[i * 32 + l15];
        gv[1] = gb[i * 32 + 16 + l15];
        float xi0, xi1, xi2, px[2], py[2], pz[2];
        if (PAD) {
            const f32x4 x4 = *(const f32x4*)(pp + (size_t)pt * 4);
            xi0 = x4[0]; xi1 = x4[1]; xi2 = x4[2];
            #pragma unroll
            for (int mt = 0; mt < 2; ++mt) {
                const f32x4 p4 = *(const f32x4*)(ppb + (((unsigned)gv[mt]) << 2));
                px[mt] = p4[0]; py[mt] = p4[1]; pz[mt] = p4[2];
            }
        } else {
            xi0 = points[(size_t)pt * 3];
            xi1 = points[(size_t)pt * 3 + 1];
            xi2 = points[(size_t)pt * 3 + 2];
            #pragma unroll
            for (int mt = 0; mt < 2; ++mt) {
                const float* ppt = points + (size_t)(bb + gv[mt]) * 3;
                px[mt] = ppt[0]; py[mt] = ppt[1]; pz[mt] = ppt[2];
            }
        }
        #pragma unroll
        for (int mt = 0; mt < 2; ++mt) {
            const float dx = xi0 - px[mt], dy = xi1 - py[mt], dz = xi2 - pz[mt];
            const float dist = __builtin_amdgcn_sqrtf(dx * dx + dy * dy + dz * dz);
            u32x4 u = {0u, 0u, 0u, 0u};
            if (quad == 0) {
                u[0] = pkbf(xi0, xi1); u[1] = pkbf(xi2, px[mt]);
                u[2] = pkbf(py[mt], pz[mt]); u[3] = pkbf(dx, dy);
            } else if (quad == 1) {
                u[0] = pkbf(dz, dist);
            }
            __builtin_memcpy(&ageo[mt], &u, 16);
        }
    };

    // FRONT: pos-MLP MFMA + epilogue1 (writes hbuf slot) + GCM MFMAs -> acc2
    auto FRONT = [&](short* hb, const f32x4 (&f4)[2][4], const bf16x8 (&ageo)[2],
                     f32x4 (&acc2)[2][4]) {
        __builtin_amdgcn_s_setprio(1);
        f32x4 acc1[2][4];
        #pragma unroll
        for (int mt = 0; mt < 2; ++mt)
            #pragma unroll
            for (int nt = 0; nt < 4; ++nt)
                acc1[mt][nt] = __builtin_amdgcn_mfma_f32_16x16x32_bf16(
                    ageo[mt], bposf[nt], zero4, 0, 0, 0);
        __builtin_amdgcn_s_setprio(0);

        #pragma unroll
        for (int mt = 0; mt < 2; ++mt)
            #pragma unroll
            for (int r = 0; r < 4; ++r) {
                const int k = mt * 16 + quad * 4 + r;
                float v[4];
                #pragma unroll
                for (int j = 0; j < 4; ++j)
                    v[j] = f4[mt][r][j] + fmaxf(ps1[j] * acc1[mt][j][r] + pb1[j], 0.f);
                u32x2 hv = { pkbf(v[0], v[1]), pkbf(v[2], v[3]) };
                *(u32x2*)&hb[k * HSTR + c4] = hv;
            }

        bf16x8 a2[2][2];
        #pragma unroll
        for (int mt = 0; mt < 2; ++mt)
            #pragma unroll
            for (int ks = 0; ks < 2; ++ks)
                a2[mt][ks] = *(const bf16x8*)&hb[(mt * 16 + l15) * HSTR + ks * 32 + quad * 8];
        __builtin_amdgcn_s_setprio(1);
        #pragma unroll
        for (int nt = 0; nt < 4; ++nt) {
            const bf16x8 b0 = *(const bf16x8*)&wb2[((nt * 2 + 0) * 64 + l) * 8];
            const bf16x8 b1 = *(const bf16x8*)&wb2[((nt * 2 + 1) * 64 + l) * 8];
            #pragma unroll
            for (int mt = 0; mt < 2; ++mt) {
                f32x4 a = __builtin_amdgcn_mfma_f32_16x16x32_bf16(a2[mt][0], b0, zero4, 0, 0, 0);
                acc2[mt][nt] = __builtin_amdgcn_mfma_f32_16x16x32_bf16(a2[mt][1], b1, a, 0, 0, 0);
            }
        }
        __builtin_amdgcn_s_setprio(0);
    };

    // BACK: bn2+relu, attention softmax (shift-invariant), pool, resstage
    auto BACK = [&](int i, const f32x4 (&acc2)[2][4], const f32x4& resid) {
        float res[4];
        {
            float sp[4], mk[4];
            #pragma unroll
            for (int nt = 0; nt < 4; ++nt) {
                sp[nt] = 0.f; mk[nt] = 0.f;
                #pragma unroll
                for (int mt = 0; mt < 2; ++mt)
                    #pragma unroll
                    for (int r = 0; r < 4; ++r) {
                        const float h2 = fmaxf(ps2[nt] * acc2[mt][nt][r] + pb2[nt], 0.f);
                        sp[nt] += h2 * wat[mt][r];
                        mk[nt] = fmaxf(mk[nt], h2);
                    }
                sp[nt] += __shfl_xor(sp[nt], 16);
                sp[nt] += __shfl_xor(sp[nt], 32);
                mk[nt] = fmaxf(mk[nt], __shfl_xor(mk[nt], 16));
                mk[nt] = fmaxf(mk[nt], __shfl_xor(mk[nt], 32));
            }
            float e[4], s = 0.f;
            #pragma unroll
            for (int nt = 0; nt < 4; ++nt) { e[nt] = __expf(sp[nt] + battv); s += e[nt]; }
            #pragma unroll
            for (int o = 1; o < 16; o <<= 1) s += __shfl_xor(s, o);
            const float inv = __builtin_amdgcn_rcpf(s);
            #pragma unroll
            for (int nt = 0; nt < 4; ++nt)
                res[nt] = e[nt] * inv * mk[nt] + resid[nt];
        }
        if (quad == 0) {
            u32x2 rv = { pkbf(res[0], res[1]), pkbf(res[2], res[3]) };
            *(u32x2*)&resstage[(w * PPW + i) * RSTR + c4] = rv;
        }
    };

    short* hb0 = &hbuf[w][0][0];
    short* hb1 = &hbuf[w][1][0];

    // ---- prologue: indices for pair 0/1, data for pair 0 ----
    i32x4 giA0[2], giA1[2], giB0[2], giB1[2];
    LOADI(0, giA0); LOADI(1, giA1);
    LOADI(2, giB0); LOADI(3, giB1);
    f32x4  f4A0[2][4], f4A1[2][4], f4B0[2][4], f4B1[2][4];
    bf16x8 agA0[2], agA1[2], agB0[2], agB1[2];
    f32x4  rsA0, rsA1, rsB0, rsB1;
    LOADD(0, giA0, f4A0, agA0, rsA0);
    LOADD(1, giA1, f4A1, agA1, rsA1);

    __syncthreads();   // weight LDS ready

    // ---- paired ping-pong: 2 pairs (4 points) per iteration ----
    #pragma unroll
    for (int ip = 0; ip < PPW; ip += 4) {
        // ----- pair A: points ip, ip+1 -----
        f32x4 accA0[2][4], accA1[2][4];
        FRONT(hb0, f4A0, agA0, accA0);
        FRONT(hb1, f4A1, agA1, accA1);
        if (ip + 2 < PPW) {
            LOADD(ip + 2, giB0, f4B0, agB0, rsB0);
            LOADD(ip + 3, giB1, f4B1, agB1, rsB1);
            if (ip + 4 < PPW) { LOADI(ip + 4, giA0); LOADI(ip + 5, giA1); }
        }
        BACK(ip, accA0, rsA0);
        BACK(ip + 1, accA1, rsA1);

        // ----- pair B: points ip+2, ip+3 -----
        if (ip + 2 < PPW) {
            f32x4 accB0[2][4], accB1[2][4];
            FRONT(hb0, f4B0, agB0, accB0);
            FRONT(hb1, f4B1, agB1, accB1);
            if (ip + 4 < PPW) {
                LOADD(ip + 4, giA0, f4A0, agA0, rsA0);
                LOADD(ip + 5, giA1, f4A1, agA1, rsA1);
                if (ip + 6 < PPW) { LOADI(ip + 6, giB0); LOADI(ip + 7, giB1); }
            }
            BACK(ip + 2, accB0, rsB0);
            BACK(ip + 3, accB1, rsB1);
        }
    }

    __syncthreads();

    // ---------- phase D: batched out-matmul + LayerNorm + relu ----------
    // 4 groups of 16 points; wave w -> group w, all 4 LN rows
    {
        const f32x4 lngv  = *(const f32x4*)(lng + c4);
        const f32x4 lnbv  = *(const f32x4*)(lnb + c4);
        const f32x4 boutv = *(const f32x4*)(bout + c4);
        bf16x8 a3[2];
        #pragma unroll
        for (int ks = 0; ks < 2; ++ks)
            a3[ks] = *(const bf16x8*)&resstage[(w * 16 + l15) * RSTR + ks * 32 + quad * 8];
        f32x4 acc3[4];
        #pragma unroll
        for (int nt = 0; nt < 4; ++nt) {
            const bf16x8 b0 = *(const bf16x8*)&wb3[((nt * 2 + 0) * 64 + l) * 8];
            const bf16x8 b1 = *(const bf16x8*)&wb3[((nt * 2 + 1) * 64 + l) * 8];
            f32x4 a = __builtin_amdgcn_mfma_f32_16x16x32_bf16(a3[0], b0, zero4, 0, 0, 0);
            acc3[nt] = __builtin_amdgcn_mfma_f32_16x16x32_bf16(a3[1], b1, a, 0, 0, 0);
        }
        #pragma unroll
        for (int u = 0; u < 4; ++u) {
            float y[4], s = 0.f;
            #pragma unroll
            for (int nt = 0; nt < 4; ++nt) { y[nt] = acc3[nt][u] + boutv[nt]; s += y[nt]; }
            #pragma unroll
            for (int o = 1; o < 16; o <<= 1) s += __shfl_xor(s, o);
            const float mu = s * (1.f / 64.f);
            float dv[4], v2 = 0.f;
            #pragma unroll
            for (int nt = 0; nt < 4; ++nt) { dv[nt] = y[nt] - mu; v2 += dv[nt] * dv[nt]; }
            #pragma unroll
            for (int o = 1; o < 16; o <<= 1) v2 += __shfl_xor(v2, o);
            const float rs = rsqrtf(v2 * (1.f / 64.f) + EPSF);
            const int pto = blk * PPB + w * 16 + quad * 4 + u;
            f32x4 ov;
            #pragma unroll
            for (int nt = 0; nt < 4; ++nt)
                ov[nt] = fmaxf(lngv[nt] * dv[nt] * rs + lnbv[nt], 0.f);
            *(f32x4*)(out + (size_t)pto * 64 + c4) = ov;
        }
    }
}

extern "C" void kernel_launch(void* const* d_in, const int* in_sizes, int n_in,
                              void* d_out, int out_size, void* d_ws, size_t ws_size,
                              hipStream_t stream) {
    const float* points   = (const float*)d_in[0];
    const float* features = (const float*)d_in[1];
    const int*   gidxp    = (const int*)d_in[2];
    const bool   pad      = (ws_size >= PP_BYTES);
    float* pp = (float*)d_ws;
    if (pad) {
        hipLaunchKernelGGL(prep_points, dim3((B_ * N_ + 255) / 256), dim3(256), 0, stream,
                           points, pp);
        hipLaunchKernelGGL((bridgenet14<true>), dim3(NWG), dim3(256), 0, stream,
            points, pp, features, gidxp,
            (const float*)d_in[3],  (const float*)d_in[4],
            (const float*)d_in[5],  (const float*)d_in[6],  (const float*)d_in[7],  (const float*)d_in[8],
            (const float*)d_in[9],  (const float*)d_in[10],
            (const float*)d_in[11], (const float*)d_in[12], (const float*)d_in[13], (const float*)d_in[14],
            (const float*)d_in[15], (const float*)d_in[16],
            (const float*)d_in[17], (const float*)d_in[18],
            (const float*)d_in[19], (const float*)d_in[20],
            (float*)d_out);
    } else {
        hipLaunchKernelGGL((bridgenet14<false>), dim3(NWG), dim3(256), 0, stream,
            points, pp, features, gidxp,
            (const float*)d_in[3],  (const float*)d_in[4],
            (const float*)d_in[5],  (const float*)d_in[6],  (const float*)d_in[7],  (const float*)d_in[8],
            (const float*)d_in[9],  (const float*)d_in[10],
            (const float*)d_in[11], (const float*)d_in[12], (const float*)d_in[13], (const float*)d_in[14],
            (const float*)d_in[15], (const float*)d_in[16],
            (const float*)d_in[17], (const float*)d_in[18],
            (const float*)d_in[19], (const float*)d_in[20],
            (float*)d_out);
    }
}